// Round 1
// baseline (154.992 us; speedup 1.0000x reference)
//
#include <hip/hip_runtime.h>

#define B 32
#define N 9
#define M 128
#define V 512
#define H 256
#define K 8
#define NT 12           // TYPES-9
#define KO 80           // K*(N+1)
#define NP1 10          // N+1
#define NEWV_ROWS (B*20*3)   // rows of V floats to zero for new_v

__device__ __forceinline__ float wave_sum(float v) {
    #pragma unroll
    for (int off = 32; off > 0; off >>= 1) v += __shfl_xor(v, off, 64);
    return v;
}
__device__ __forceinline__ float wave_max(float v) {
    #pragma unroll
    for (int off = 32; off > 0; off >>= 1) v = fmaxf(v, __shfl_xor(v, off, 64));
    return v;
}

// ---------------- kernel 1: per-sample template-slot selection ----------------
__global__ __launch_bounds__(256) void k_select(
    const float* __restrict__ type_emb, const float* __restrict__ W,
    const float* __restrict__ bias, const float* __restrict__ gumbel,
    const int* __restrict__ types, const int* __restrict__ spans,
    int* __restrict__ jstar)
{
    const int b = blockIdx.x;
    const int t = threadIdx.x;
    const int typ = types[b];
    const int span = spans[b];

    __shared__ float emb_s[H];
    __shared__ float logits_s[KO];

    emb_s[t] = type_emb[typ * H + t];
    __syncthreads();

    const int wave = t >> 6, lane = t & 63;
    const long base = (long)((span - 2) * NT + (typ - 9)) * KO;

    #pragma unroll
    for (int i = 0; i < KO / 4; ++i) {          // 20 outputs per wave
        const int o = wave * (KO / 4) + i;
        const float* w = W + (base + o) * H;
        float s = w[lane      ] * emb_s[lane      ]
                + w[lane +  64] * emb_s[lane +  64]
                + w[lane + 128] * emb_s[lane + 128]
                + w[lane + 192] * emb_s[lane + 192];
        s = wave_sum(s);
        if (lane == 0) logits_s[o] = s + bias[base + o];
    }
    __syncthreads();

    if (t < K) {
        const int k = t;
        float best = -3.0e38f;
        int bj = 0;
        #pragma unroll
        for (int j = 0; j < NP1; ++j) {
            if (j <= span) {                     // validity mask (else -1e30)
                float v = logits_s[k * NP1 + j] + gumbel[(b * K + k) * NP1 + j];
                if (v > best) { best = v; bj = j; }   // first-max tie-break
            }
        }
        if (typ == 20) bj = (k == 0) ? 1 : 0;    // fixed start template
        jstar[b * K + k] = bj;
    }
}

// ---------------- kernel 2: raw_len per (b,k) ----------------
// raw_len = 1 + last row m where argmax_v(decoding[m,:]) != 0,
// i.e. where max_{v>=1} x[m,v] > x[m,0]  (tie -> index 0 -> PAD)
__global__ __launch_bounds__(256) void k_rawlen(
    const float* __restrict__ dec, const int* __restrict__ jstar,
    int* __restrict__ rawlen)
{
    const int blk = blockIdx.x;
    const int b = blk >> 3, k = blk & 7;
    (void)k;
    const int j = jstar[blk];
    const int t = threadIdx.x, wave = t >> 6, lane = t & 63;
    __shared__ int part[4];

    if (j == 0) { if (t == 0) rawlen[blk] = 0; return; }

    const float* src = dec + (long)(b * N + (j - 1)) * M * V;
    int best = 0;
    for (int m = wave; m < M; m += 4) {
        const float4* row = (const float4*)(src + (long)m * V);
        float4 a = row[lane];
        float4 c = row[lane + 64];
        float x0 = 0.0f, loc;
        if (lane == 0) {                 // exclude v==0 from the max
            x0 = a.x;
            loc = fmaxf(fmaxf(a.y, a.z), a.w);
        } else {
            loc = fmaxf(fmaxf(a.x, a.y), fmaxf(a.z, a.w));
        }
        loc = fmaxf(loc, fmaxf(fmaxf(c.x, c.y), fmaxf(c.z, c.w)));
        float mx = wave_max(loc);
        x0 = __shfl(x0, 0, 64);
        if (mx > x0) best = m + 1;       // uniform across lanes
    }
    if (lane == 0) part[wave] = best;
    __syncthreads();
    if (t == 0) {
        int r = 0;
        #pragma unroll
        for (int w = 0; w < 4; ++w) r = max(r, part[w]);
        rawlen[blk] = r;
    }
}

// ---------------- kernel 3: write output (copy rows / zero rows / zero new_v) --
__global__ __launch_bounds__(128) void k_write(
    const float* __restrict__ dec, const int* __restrict__ jstar,
    const int* __restrict__ rawlen, float* __restrict__ out)
{
    const int blk = blockIdx.x;
    const int t = threadIdx.x;

    if (blk >= B * M) {                  // zero new_v region
        const int r = blk - B * M;       // 0 .. NEWV_ROWS-1
        float4* dst = (float4*)(out + (long)B * M * V + (long)r * V);
        dst[t] = make_float4(0.f, 0.f, 0.f, 0.f);
        return;
    }

    const int b = blk / M, m = blk % M;

    // clipped sequential concat: find which k (if any) owns output row m
    int found_k = -1, src_m = 0;
    int cum = 0;
    #pragma unroll
    for (int k = 0; k < K; ++k) {
        int e = cum + rawlen[b * K + k];
        e = min(e, M);
        if (found_k < 0 && m < e) { found_k = k; src_m = m - cum; }
        cum = e;
    }

    float4* dst = (float4*)(out + ((long)b * M + m) * V);
    if (found_k < 0) {
        dst[t] = make_float4(0.f, 0.f, 0.f, 0.f);
    } else {
        const int j = jstar[b * K + found_k];        // > 0 whenever rawlen > 0
        const float4* src = (const float4*)(dec + ((long)(b * N + (j - 1)) * M + src_m) * V);
        dst[t] = src[t];
    }
}

extern "C" void kernel_launch(void* const* d_in, const int* in_sizes, int n_in,
                              void* d_out, int out_size, void* d_ws, size_t ws_size,
                              hipStream_t stream) {
    const float* dec      = (const float*)d_in[0];
    const float* type_emb = (const float*)d_in[1];
    const float* W        = (const float*)d_in[2];
    const float* bias     = (const float*)d_in[3];
    const float* gumbel   = (const float*)d_in[4];
    const int*   types    = (const int*)d_in[5];
    const int*   spans    = (const int*)d_in[6];
    float* out = (float*)d_out;

    int* jstar  = (int*)d_ws;            // B*K ints
    int* rawlen = jstar + B * K;         // B*K ints

    k_select<<<B, 256, 0, stream>>>(type_emb, W, bias, gumbel, types, spans, jstar);
    k_rawlen<<<B * K, 256, 0, stream>>>(dec, jstar, rawlen);
    k_write<<<B * M + NEWV_ROWS, 128, 0, stream>>>(dec, jstar, rawlen, out);
}

// Round 2
// 126.436 us; speedup vs baseline: 1.2258x; 1.2258x over previous
//
#include <hip/hip_runtime.h>

#define B 32
#define N 9
#define M 128
#define V 512
#define H 256
#define K 8
#define NT 12            // TYPES-9
#define NP1 10           // N+1
#define SPLITS 4
#define ROWS_PER_SPLIT 32
#define NEWV_ROWS (B*20*3)

__device__ __forceinline__ float wave_sum(float v) {
    #pragma unroll
    for (int off = 32; off > 0; off >>= 1) v += __shfl_xor(v, off, 64);
    return v;
}

// ---- fused kernel: per-(b,k) slot selection + partial raw_len over 32 rows ----
// grid = B*K*SPLITS blocks of 256 threads; block = ((b*K+k)*SPLITS + s)
__global__ __launch_bounds__(256) void k_sel_rawlen(
    const float* __restrict__ dec, const float* __restrict__ type_emb,
    const float* __restrict__ W, const float* __restrict__ bias,
    const float* __restrict__ gumbel, const int* __restrict__ types,
    const int* __restrict__ spans,
    int* __restrict__ jstar, int* __restrict__ part)
{
    const int blk = blockIdx.x;
    const int s  = blk & (SPLITS - 1);
    const int bk = blk >> 2;             // b*K + k
    const int b  = bk >> 3, k = bk & 7;
    const int t = threadIdx.x, wave = t >> 6, lane = t & 63;

    __shared__ float logits_s[NP1];
    __shared__ int   j_s;
    __shared__ int   best_s[4];

    if (wave == 0) {
        const int typ  = types[b];
        const int span = spans[b];
        const long base = ((long)(span - 2) * NT + (typ - 9)) * (K * NP1) + k * NP1;
        const float e0 = type_emb[typ * H + lane      ];
        const float e1 = type_emb[typ * H + lane +  64];
        const float e2 = type_emb[typ * H + lane + 128];
        const float e3 = type_emb[typ * H + lane + 192];
        #pragma unroll
        for (int j = 0; j < NP1; ++j) {
            const float* w = W + (base + j) * H;
            float ssum = w[lane      ] * e0 + w[lane +  64] * e1
                       + w[lane + 128] * e2 + w[lane + 192] * e3;
            ssum = wave_sum(ssum);
            if (lane == 0) logits_s[j] = ssum;
        }
        if (lane == 0) {
            int bj = 0;
            if (typ == 20) {
                bj = (k == 0) ? 1 : 0;           // fixed start template
            } else {
                float bestv = -3.0e38f;
                for (int j = 0; j <= span; ++j) { // validity mask; span<=9
                    float v = logits_s[j] + bias[base + j] + gumbel[bk * NP1 + j];
                    if (v > bestv) { bestv = v; bj = j; }  // first-max tie-break
                }
            }
            j_s = bj;
        }
    }
    __syncthreads();
    const int j = j_s;
    if (t == 0) jstar[bk] = j;           // redundant across s-blocks: same value

    // raw_len partial: last row m in this split with argmax_v != 0 (PAD)
    int best = 0;
    if (j > 0) {
        const float* src = dec + ((long)(b * N + (j - 1)) * M) * V;
        const int m0 = s * ROWS_PER_SPLIT + wave * 8;
        #pragma unroll
        for (int i = 0; i < 8; ++i) {
            const int m = m0 + i;
            const float4* row = (const float4*)(src + (long)m * V);
            float4 a = row[lane];
            float4 c = row[lane + 64];
            float x0 = __shfl(a.x, 0, 64);       // x[m][0] (PAD logit)
            float loc = (lane == 0) ? fmaxf(fmaxf(a.y, a.z), a.w)
                                    : fmaxf(fmaxf(a.x, a.y), fmaxf(a.z, a.w));
            loc = fmaxf(loc, fmaxf(fmaxf(c.x, c.y), fmaxf(c.z, c.w)));
            if (__ballot(loc > x0)) best = m + 1; // strict >: tie -> PAD (first idx)
        }
    }
    if (lane == 0) best_s[wave] = best;
    __syncthreads();
    if (t == 0)
        part[blk] = max(max(best_s[0], best_s[1]), max(best_s[2], best_s[3]));
}

// ---- output writer: one block per output row (or new_v row) ----
__global__ __launch_bounds__(128) void k_write(
    const float* __restrict__ dec, const int* __restrict__ jstar,
    const int* __restrict__ part, float* __restrict__ out)
{
    const int blk = blockIdx.x;
    const int t = threadIdx.x;

    if (blk >= B * M) {                  // zero the new_v region
        const int r = blk - B * M;
        float4* dst = (float4*)(out + (long)B * M * V + (long)r * V);
        dst[t] = make_float4(0.f, 0.f, 0.f, 0.f);
        return;
    }

    const int b = blk >> 7, m = blk & 127;

    // clipped sequential concat: which k (if any) owns output row m
    int found_k = -1, src_m = 0, cum = 0;
    #pragma unroll
    for (int k = 0; k < K; ++k) {
        const int* p = part + (b * K + k) * SPLITS;
        const int rl = max(max(p[0], p[1]), max(p[2], p[3]));
        const int e = min(cum + rl, M);
        if (found_k < 0 && m < e) { found_k = k; src_m = m - cum; }
        cum = e;
    }

    float4* dst = (float4*)(out + ((long)b * M + m) * V);
    if (found_k < 0) {
        dst[t] = make_float4(0.f, 0.f, 0.f, 0.f);
    } else {
        const int j = jstar[b * K + found_k];    // > 0 whenever rl > 0
        const float4* src = (const float4*)(dec + ((long)(b * N + (j - 1)) * M + src_m) * V);
        dst[t] = src[t];
    }
}

extern "C" void kernel_launch(void* const* d_in, const int* in_sizes, int n_in,
                              void* d_out, int out_size, void* d_ws, size_t ws_size,
                              hipStream_t stream) {
    const float* dec      = (const float*)d_in[0];
    const float* type_emb = (const float*)d_in[1];
    const float* W        = (const float*)d_in[2];
    const float* bias     = (const float*)d_in[3];
    const float* gumbel   = (const float*)d_in[4];
    const int*   types    = (const int*)d_in[5];
    const int*   spans    = (const int*)d_in[6];
    float* out = (float*)d_out;

    int* jstar = (int*)d_ws;                    // B*K ints
    int* part  = jstar + B * K;                 // B*K*SPLITS ints

    k_sel_rawlen<<<B * K * SPLITS, 256, 0, stream>>>(
        dec, type_emb, W, bias, gumbel, types, spans, jstar, part);
    k_write<<<B * M + NEWV_ROWS, 128, 0, stream>>>(dec, jstar, part, out);
}

// Round 6
// 122.974 us; speedup vs baseline: 1.2604x; 1.0282x over previous
//
#include <hip/hip_runtime.h>

#define B 32
#define N 9
#define M 128
#define V 512
#define H 256
#define K 8
#define NT 12            // TYPES-9
#define NP1 10           // N+1
#define SPLITS 8
#define ROWS_PER_SPLIT 16        // M / SPLITS
#define SCAN_BLKS (B*N*SPLITS)   // 2304
#define SEL_BLKS (B*K)           // 256
#define NEWV_ROWS (B*20*3)       // 1920 rows of V floats (new_v, all zero)

__device__ __forceinline__ float wave_sum(float v) {
    #pragma unroll
    for (int off = 32; off > 0; off >>= 1) v += __shfl_xor(v, off, 64);
    return v;
}

// ---- kernel A: two independent roles ----
//  blocks [0, SCAN_BLKS): scan slab rows -> partial rawlen per (b,slab,split)
//  blocks [SCAN_BLKS, +SEL_BLKS): per-(b,k) template-slot selection -> jstar
__global__ __launch_bounds__(256) void k_scan_sel(
    const float* __restrict__ dec, const float* __restrict__ type_emb,
    const float* __restrict__ W, const float* __restrict__ bias,
    const float* __restrict__ gumbel, const int* __restrict__ types,
    const int* __restrict__ spans,
    int* __restrict__ jstar, int* __restrict__ part)
{
    const int blk = blockIdx.x;
    const int t = threadIdx.x, wave = t >> 6, lane = t & 63;

    if (blk < SCAN_BLKS) {
        const int s  = blk & (SPLITS - 1);
        const int bs = blk >> 3;                 // b*N + slab
        const int b = bs / N, slab = bs % N;
        const int typ = types[b], span = spans[b];
        if (slab >= span) return;                // j = slab+1 > span: never selectable
        if (typ == 20 && slab != 0) return;      // start template only uses slab 0

        const float* src = dec + (long)bs * M * V;
        int best = 0;
        const int m0 = s * ROWS_PER_SPLIT + wave * 4;
        #pragma unroll
        for (int i = 0; i < 4; ++i) {
            const int m = m0 + i;
            const float4* row = (const float4*)(src + (long)m * V);
            float4 a = row[lane];
            float4 c = row[lane + 64];
            float x0 = __shfl(a.x, 0, 64);       // x[m][0]  (PAD logit)
            float loc = (lane == 0) ? fmaxf(fmaxf(a.y, a.z), a.w)
                                    : fmaxf(fmaxf(a.x, a.y), fmaxf(a.z, a.w));
            loc = fmaxf(loc, fmaxf(fmaxf(c.x, c.y), fmaxf(c.z, c.w)));
            if (__ballot(loc > x0)) best = m + 1; // strict >: tie -> PAD (first idx)
        }
        __shared__ int bs_s[4];
        if (lane == 0) bs_s[wave] = best;
        __syncthreads();
        if (t == 0)
            part[blk] = max(max(bs_s[0], bs_s[1]), max(bs_s[2], bs_s[3]));
    } else {
        const int bk = blk - SCAN_BLKS;          // b*K + k
        const int b = bk >> 3, k = bk & 7;
        const int typ = types[b], span = spans[b];
        __shared__ float logits_s[NP1];

        const long base = ((long)(span - 2) * NT + (typ - 9)) * (K * NP1) + k * NP1;
        const float4 e4 = ((const float4*)(type_emb + typ * H))[lane];
        for (int j = wave; j < NP1; j += 4) {    // waves split the 10 outputs
            const float4 w4 = ((const float4*)(W + (base + j) * H))[lane];
            float ssum = w4.x * e4.x + w4.y * e4.y + w4.z * e4.z + w4.w * e4.w;
            ssum = wave_sum(ssum);
            if (lane == 0)
                logits_s[j] = ssum + bias[base + j] + gumbel[bk * NP1 + j];
        }
        __syncthreads();
        if (t == 0) {
            int bj = 0;
            if (typ == 20) {
                bj = (k == 0) ? 1 : 0;           // fixed start template
            } else {
                float bestv = -3.0e38f;
                for (int j = 0; j <= span; ++j) { // validity mask; span<=9
                    const float v = logits_s[j];
                    if (v > bestv) { bestv = v; bj = j; }  // first-max tie-break
                }
            }
            jstar[bk] = bj;
        }
    }
}

// ---- kernel B: write output; 256 thr = 2 output rows per block ----
__global__ __launch_bounds__(256) void k_write(
    const float* __restrict__ dec, const int* __restrict__ jstar,
    const int* __restrict__ part, float* __restrict__ out)
{
    const int blk = blockIdx.x;
    const int t = threadIdx.x;
    const int half = t >> 7, t1 = t & 127;       // which of the 2 rows / lane-in-row

    if (blk >= B * (M / 2)) {                    // zero the new_v region
        const int r = (blk - B * (M / 2)) * 2 + half;
        float4* dst = (float4*)(out + (long)B * M * V + (long)r * V);
        dst[t1] = make_float4(0.f, 0.f, 0.f, 0.f);
        return;
    }

    const int b = blk >> 6;
    const int m = ((blk & 63) << 1) + half;

    // clipped sequential concat: which k (if any) owns output row m
    int found_k = -1, src_m = 0, cum = 0;
    #pragma unroll
    for (int k = 0; k < K; ++k) {
        const int j = jstar[b * K + k];
        int rl = 0;
        if (j > 0) {
            const int* p = part + ((b * N + (j - 1)) << 3);
            #pragma unroll
            for (int q = 0; q < SPLITS; ++q) rl = max(rl, p[q]);
        }
        const int e = min(cum + rl, M);
        if (found_k < 0 && m < e) { found_k = k; src_m = m - cum; }
        cum = e;
    }

    float4* dst = (float4*)(out + ((long)b * M + m) * V);
    if (found_k < 0) {
        dst[t1] = make_float4(0.f, 0.f, 0.f, 0.f);
    } else {
        const int j = jstar[b * K + found_k];    // > 0 whenever rl > 0
        const float4* src = (const float4*)(dec + ((long)(b * N + (j - 1)) * M + src_m) * V);
        dst[t1] = src[t1];
    }
}

extern "C" void kernel_launch(void* const* d_in, const int* in_sizes, int n_in,
                              void* d_out, int out_size, void* d_ws, size_t ws_size,
                              hipStream_t stream) {
    const float* dec      = (const float*)d_in[0];
    const float* type_emb = (const float*)d_in[1];
    const float* W        = (const float*)d_in[2];
    const float* bias     = (const float*)d_in[3];
    const float* gumbel   = (const float*)d_in[4];
    const int*   types    = (const int*)d_in[5];
    const int*   spans    = (const int*)d_in[6];
    float* out = (float*)d_out;

    int* jstar = (int*)d_ws;                     // B*K ints
    int* part  = jstar + B * K;                  // B*N*SPLITS ints

    k_scan_sel<<<SCAN_BLKS + SEL_BLKS, 256, 0, stream>>>(
        dec, type_emb, W, bias, gumbel, types, spans, jstar, part);
    k_write<<<B * (M / 2) + NEWV_ROWS / 2, 256, 0, stream>>>(dec, jstar, part, out);
}

// Round 8
// 118.473 us; speedup vs baseline: 1.3082x; 1.0380x over previous
//
#include <hip/hip_runtime.h>

#define B 32
#define N 9
#define M 128
#define V 512
#define H 256
#define K 8
#define NT 12            // TYPES-9
#define NP1 10           // N+1
#define CHUNK 16         // backward-scan chunk rows
#define SCAN_BLKS (B*N)          // 288
#define SEL_BLKS (B*K)           // 256
#define NEWV_ROWS (B*20*3)       // 1920 rows of V floats (new_v, all zero)
#define NEWV_BLKS (NEWV_ROWS/2)  // 960

__device__ __forceinline__ float wave_sum(float v) {
    #pragma unroll
    for (int off = 32; off > 0; off >>= 1) v += __shfl_xor(v, off, 64);
    return v;
}

// ---- kernel A: three independent roles ----
//  [0, SCAN_BLKS): backward chunked scan -> rawlen per (b,slab)
//  [SCAN_BLKS, +SEL_BLKS): per-(b,k) template-slot selection -> jstar
//  [SCAN_BLKS+SEL_BLKS, +NEWV_BLKS): zero the new_v output region
__global__ __launch_bounds__(256) void k_scan_sel(
    const float* __restrict__ dec, const float* __restrict__ type_emb,
    const float* __restrict__ W, const float* __restrict__ bias,
    const float* __restrict__ gumbel, const int* __restrict__ types,
    const int* __restrict__ spans,
    int* __restrict__ jstar, int* __restrict__ part, float* __restrict__ out)
{
    const int blk = blockIdx.x;
    const int t = threadIdx.x, wave = t >> 6, lane = t & 63;

    if (blk < SCAN_BLKS) {
        // ---- rawlen: scan rows backward, early-exit on first qualifying chunk.
        // A row m qualifies iff max_{v>=1} x[m][v] > x[m][0]  (strict: tie -> PAD).
        const int bs = blk;                      // b*N + slab
        const int b = bs / N, slab = bs % N;
        const int typ = types[b], span = spans[b];
        if (slab >= span) return;                // j = slab+1 > span: never selectable
        if (typ == 20 && slab != 0) return;      // start template only uses slab 0

        const float* src = dec + (long)bs * M * V;
        __shared__ int chunk_best;
        for (int c = 0; c < M / CHUNK; ++c) {    // chunks from the end: rows [M-16(c+1), M-16c)
            if (t == 0) chunk_best = 0;
            __syncthreads();
            const int mbase = M - CHUNK * (c + 1) + wave * (CHUNK / 4);
            int best = 0;
            #pragma unroll
            for (int i = 0; i < CHUNK / 4; ++i) {
                const int m = mbase + i;
                const float4* row = (const float4*)(src + (long)m * V);
                float4 a = row[lane];
                float4 c4 = row[lane + 64];
                float x0 = __shfl(a.x, 0, 64);   // x[m][0]  (PAD logit)
                float loc = (lane == 0) ? fmaxf(fmaxf(a.y, a.z), a.w)
                                        : fmaxf(fmaxf(a.x, a.y), fmaxf(a.z, a.w));
                loc = fmaxf(loc, fmaxf(fmaxf(c4.x, c4.y), fmaxf(c4.z, c4.w)));
                if (__ballot(loc > x0)) best = m + 1;
            }
            if (lane == 0 && best) atomicMax(&chunk_best, best);
            __syncthreads();
            if (chunk_best) {                    // uniform across block
                if (t == 0) part[bs] = chunk_best;
                return;
            }
        }
        if (t == 0) part[bs] = 0;                // fully-PAD slab
    } else if (blk < SCAN_BLKS + SEL_BLKS) {
        // ---- template-slot selection
        const int bk = blk - SCAN_BLKS;          // b*K + k
        const int b = bk >> 3, k = bk & 7;
        const int typ = types[b], span = spans[b];
        __shared__ float logits_s[NP1];

        const long base = ((long)(span - 2) * NT + (typ - 9)) * (K * NP1) + k * NP1;
        const float4 e4 = ((const float4*)(type_emb + typ * H))[lane];
        for (int j = wave; j < NP1; j += 4) {    // waves split the 10 outputs
            const float4 w4 = ((const float4*)(W + (base + j) * H))[lane];
            float ssum = w4.x * e4.x + w4.y * e4.y + w4.z * e4.z + w4.w * e4.w;
            ssum = wave_sum(ssum);
            if (lane == 0)
                logits_s[j] = ssum + bias[base + j] + gumbel[bk * NP1 + j];
        }
        __syncthreads();
        if (t == 0) {
            int bj = 0;
            if (typ == 20) {
                bj = (k == 0) ? 1 : 0;           // fixed start template
            } else {
                float bestv = -3.0e38f;
                for (int j = 0; j <= span; ++j) { // validity mask; span<=9
                    const float v = logits_s[j];
                    if (v > bestv) { bestv = v; bj = j; }  // first-max tie-break
                }
            }
            jstar[bk] = bj;
        }
    } else {
        // ---- zero new_v (independent of everything)
        const int half = t >> 7, t1 = t & 127;
        const int r = (blk - SCAN_BLKS - SEL_BLKS) * 2 + half;
        float4* dst = (float4*)(out + (long)B * M * V + (long)r * V);
        dst[t1] = make_float4(0.f, 0.f, 0.f, 0.f);
    }
}

// ---- kernel B: write new_d; 256 thr = 2 output rows per block ----
__global__ __launch_bounds__(256) void k_write(
    const float* __restrict__ dec, const int* __restrict__ jstar,
    const int* __restrict__ part, float* __restrict__ out)
{
    const int blk = blockIdx.x;
    const int t = threadIdx.x;
    const int half = t >> 7, t1 = t & 127;       // which of the 2 rows / lane-in-row

    const int b = blk >> 6;
    const int m = ((blk & 63) << 1) + half;

    // clipped sequential concat: which k (if any) owns output row m
    int found_k = -1, src_m = 0, cum = 0;
    #pragma unroll
    for (int k = 0; k < K; ++k) {
        const int j = jstar[b * K + k];
        const int rl = (j > 0) ? part[b * N + (j - 1)] : 0;
        const int e = min(cum + rl, M);
        if (found_k < 0 && m < e) { found_k = k; src_m = m - cum; }
        cum = e;
    }

    float4* dst = (float4*)(out + ((long)b * M + m) * V);
    if (found_k < 0) {
        dst[t1] = make_float4(0.f, 0.f, 0.f, 0.f);
    } else {
        const int j = jstar[b * K + found_k];    // > 0 whenever rl > 0
        const float4* src = (const float4*)(dec + ((long)(b * N + (j - 1)) * M + src_m) * V);
        dst[t1] = src[t1];
    }
}

extern "C" void kernel_launch(void* const* d_in, const int* in_sizes, int n_in,
                              void* d_out, int out_size, void* d_ws, size_t ws_size,
                              hipStream_t stream) {
    const float* dec      = (const float*)d_in[0];
    const float* type_emb = (const float*)d_in[1];
    const float* W        = (const float*)d_in[2];
    const float* bias     = (const float*)d_in[3];
    const float* gumbel   = (const float*)d_in[4];
    const int*   types    = (const int*)d_in[5];
    const int*   spans    = (const int*)d_in[6];
    float* out = (float*)d_out;

    int* jstar = (int*)d_ws;                     // B*K ints
    int* part  = jstar + B * K;                  // B*N ints (full rawlen per slab)

    k_scan_sel<<<SCAN_BLKS + SEL_BLKS + NEWV_BLKS, 256, 0, stream>>>(
        dec, type_emb, W, bias, gumbel, types, spans, jstar, part, out);
    k_write<<<B * (M / 2), 256, 0, stream>>>(dec, jstar, part, out);
}